// Round 12
// baseline (750.475 us; speedup 1.0000x reference)
//
#include <hip/hip_runtime.h>
#include <cstdint>
#include <cstddef>

#define FEAT 128
#define PSL2 64           // pool slices for fused agg+pool
#define BSHIFT 7          // 128 nodes per bucket
#define CAP 4096          // bucket capacity (mean 2048 for E=1.6M, N=100k)

typedef _Float16 h16;
typedef __attribute__((ext_vector_type(8))) _Float16 h16x8;
typedef __attribute__((ext_vector_type(4))) float f32x4;

// ---------- fp32 -> fp16 bulk convert (8 elems/thread) ----------
__global__ __launch_bounds__(256) void k_cvt(const float* __restrict__ X,
    h16* __restrict__ Y, int nv) {
  int i = blockIdx.x * 256 + threadIdx.x;
  if (i < nv) {
    const float* p = X + (size_t)i * 8;
    float4 a = *(const float4*)p, b = *(const float4*)(p + 4);
    h16x8 o;
    o[0] = (h16)a.x; o[1] = (h16)a.y; o[2] = (h16)a.z; o[3] = (h16)a.w;
    o[4] = (h16)b.x; o[5] = (h16)b.y; o[6] = (h16)b.z; o[7] = (h16)b.w;
    *(h16x8*)&Y[(size_t)i * 8] = o;
  }
}

// ---------- pass 1: block-level radix partition; packed (src<<7 | dstLocal) ----------
__global__ __launch_bounds__(256) void k_part(const int* __restrict__ ei,
    unsigned int* __restrict__ pair, int* __restrict__ gcur, int E, int nb) {
  __shared__ int cnt[1024];
  __shared__ int base[1024];
  int per = (E + gridDim.x - 1) / gridDim.x;
  int e0 = blockIdx.x * per;
  int e1 = min(e0 + per, E);
  for (int i = threadIdx.x; i < nb; i += 256) cnt[i] = 0;
  __syncthreads();
  for (int e = e0 + threadIdx.x; e < e1; e += 256)
    atomicAdd(&cnt[ei[E + e] >> BSHIFT], 1);
  __syncthreads();
  for (int i = threadIdx.x; i < nb; i += 256) {
    int c = cnt[i];
    base[i] = c ? atomicAdd(&gcur[i], c) : 0;
    cnt[i] = 0;   // reuse as intra-block cursor
  }
  __syncthreads();
  for (int e = e0 + threadIdx.x; e < e1; e += 256) {
    int src = ei[e];
    int dst = ei[E + e];
    int b = dst >> BSHIFT;
    int pos = base[b] + atomicAdd(&cnt[b], 1);
    if (pos < CAP) pair[(size_t)b * CAP + pos] = ((unsigned)src << BSHIFT) | (unsigned)(dst & 127);
  }
}

// ---------- small scan over bucket counts -> bucket offsets ----------
__global__ __launch_bounds__(1024) void k_bscan(const int* __restrict__ cnt,
    int* __restrict__ boffs, int* __restrict__ offs, int nb, int N, int E) {
  __shared__ int wsum[16];
  __shared__ int carry;
  int tid = threadIdx.x;
  int lane = tid & 63;
  int wid = tid >> 6;
  if (tid == 0) carry = 0;
  for (int base = 0; base < nb; base += 1024) {
    __syncthreads();
    int c0 = carry;
    int i = base + tid;
    int v = (i < nb) ? cnt[i] : 0;
    int x = v;
#pragma unroll
    for (int off = 1; off < 64; off <<= 1) {
      int t = __shfl_up(x, off);
      if (lane >= off) x += t;
    }
    if (lane == 63) wsum[wid] = x;
    __syncthreads();
    if (wid == 0) {
      int t = (lane < 16) ? wsum[lane] : 0;
#pragma unroll
      for (int off = 1; off < 16; off <<= 1) {
        int u = __shfl_up(t, off);
        if (lane >= off) t += u;
      }
      if (lane < 16) wsum[lane] = t;
    }
    __syncthreads();
    int wex = (wid == 0) ? 0 : wsum[wid - 1];
    int o = c0 + wex + (x - v);
    if (i < nb) boffs[i] = o;
    int total = wsum[15];
    __syncthreads();
    if (tid == 0) carry = c0 + total;
  }
  __syncthreads();
  if (tid == 0) { boffs[nb] = carry; offs[N] = E; }
}

// ---------- pass 2: per-bucket count/scan/scatter -> csr, offs, dinv ----------
__global__ __launch_bounds__(256) void k_bucket(const unsigned int* __restrict__ pair,
    const int* __restrict__ bcnt, const int* __restrict__ boffs,
    int* __restrict__ csr, int* __restrict__ offs, float* __restrict__ dinv,
    int N) {
  int b = blockIdx.x;
  int m = min(bcnt[b], CAP);
  __shared__ int cnt[128];
  __shared__ int noff[128];
  __shared__ int w0tot;
  if (threadIdx.x < 128) cnt[threadIdx.x] = 0;
  __syncthreads();
  const unsigned int* p = pair + (size_t)b * CAP;
  for (int i = threadIdx.x; i < m; i += 256)
    atomicAdd(&cnt[p[i] & 127u], 1);
  __syncthreads();
  int v = 0, x = 0;
  int lane = threadIdx.x & 63, w = threadIdx.x >> 6;
  if (threadIdx.x < 128) {
    v = cnt[threadIdx.x];
    x = v;
#pragma unroll
    for (int o = 1; o < 64; o <<= 1) {
      int t = __shfl_up(x, o);
      if (lane >= o) x += t;
    }
    if (threadIdx.x == 63) w0tot = x;
  }
  __syncthreads();
  int cbase = boffs[b];
  if (threadIdx.x < 128) {
    int ex = x - v + ((w == 1) ? w0tot : 0);
    int g = (b << BSHIFT) + threadIdx.x;
    if (g < N) {
      offs[g] = cbase + ex;
      dinv[g] = 1.0f / sqrtf((float)v + 1.0f);
    }
    noff[threadIdx.x] = ex;
    cnt[threadIdx.x] = 0;
  }
  __syncthreads();
  for (int i = threadIdx.x; i < m; i += 256) {
    unsigned pk = p[i];
    int d = pk & 127u;
    int pos = cbase + noff[d] + atomicAdd(&cnt[d], 1);
    csr[pos] = (int)(pk >> BSHIFT);
  }
}

// ---------- W prep: fp32 [k][col] -> fp16 transposed [col][k] ----------
__global__ __launch_bounds__(256) void k_wprep(const float* __restrict__ W,
    h16* __restrict__ WT) {
  int i = blockIdx.x * 256 + threadIdx.x;
  int k = i >> 7, c = i & 127;
  WT[c * FEAT + k] = (h16)W[(size_t)k * FEAT + c];
}

// ---------- gather core: 16 lanes/node, 16B (h16x8) per lane ----------
__device__ inline void acc8(f32x4& lo, f32x4& hi, h16x8 v) {
  lo[0] += (float)v[0]; lo[1] += (float)v[1]; lo[2] += (float)v[2]; lo[3] += (float)v[3];
  hi[0] += (float)v[4]; hi[1] += (float)v[5]; hi[2] += (float)v[6]; hi[3] += (float)v[7];
}

__device__ inline void gather_row8(const h16* __restrict__ XW,
    const int* __restrict__ offs, const int* __restrict__ csr,
    int node, int f0, f32x4& olo, f32x4& ohi) {
  f32x4 lo0 = {0,0,0,0}, hi0 = {0,0,0,0};
  f32x4 lo1 = {0,0,0,0}, hi1 = {0,0,0,0};
  f32x4 lo2 = {0,0,0,0}, hi2 = {0,0,0,0};
  f32x4 lo3 = {0,0,0,0}, hi3 = {0,0,0,0};
  h16x8 sv = *(const h16x8*)&XW[(size_t)node * FEAT + f0];   // self term
  acc8(lo0, hi0, sv);
  int s = offs[node], e = offs[node + 1];
  int i = s;
  for (; i + 8 <= e; i += 8) {
    int s0 = csr[i + 0], s1 = csr[i + 1], s2 = csr[i + 2], s3 = csr[i + 3];
    int s4 = csr[i + 4], s5 = csr[i + 5], s6 = csr[i + 6], s7 = csr[i + 7];
    h16x8 v0 = *(const h16x8*)&XW[(size_t)s0 * FEAT + f0];
    h16x8 v1 = *(const h16x8*)&XW[(size_t)s1 * FEAT + f0];
    h16x8 v2 = *(const h16x8*)&XW[(size_t)s2 * FEAT + f0];
    h16x8 v3 = *(const h16x8*)&XW[(size_t)s3 * FEAT + f0];
    h16x8 v4 = *(const h16x8*)&XW[(size_t)s4 * FEAT + f0];
    h16x8 v5 = *(const h16x8*)&XW[(size_t)s5 * FEAT + f0];
    h16x8 v6 = *(const h16x8*)&XW[(size_t)s6 * FEAT + f0];
    h16x8 v7 = *(const h16x8*)&XW[(size_t)s7 * FEAT + f0];
    acc8(lo0, hi0, v0); acc8(lo1, hi1, v1);
    acc8(lo2, hi2, v2); acc8(lo3, hi3, v3);
    acc8(lo0, hi0, v4); acc8(lo1, hi1, v5);
    acc8(lo2, hi2, v6); acc8(lo3, hi3, v7);
  }
  if (i + 4 <= e) {
    int s0 = csr[i + 0], s1 = csr[i + 1], s2 = csr[i + 2], s3 = csr[i + 3];
    h16x8 v0 = *(const h16x8*)&XW[(size_t)s0 * FEAT + f0];
    h16x8 v1 = *(const h16x8*)&XW[(size_t)s1 * FEAT + f0];
    h16x8 v2 = *(const h16x8*)&XW[(size_t)s2 * FEAT + f0];
    h16x8 v3 = *(const h16x8*)&XW[(size_t)s3 * FEAT + f0];
    acc8(lo0, hi0, v0); acc8(lo1, hi1, v1);
    acc8(lo2, hi2, v2); acc8(lo3, hi3, v3);
    i += 4;
  }
  for (; i < e; ++i) {
    int s0 = csr[i];
    h16x8 v0 = *(const h16x8*)&XW[(size_t)s0 * FEAT + f0];
    acc8(lo1, hi1, v0);
  }
  lo0[0]+=lo1[0]; lo0[1]+=lo1[1]; lo0[2]+=lo1[2]; lo0[3]+=lo1[3];
  hi0[0]+=hi1[0]; hi0[1]+=hi1[1]; hi0[2]+=hi1[2]; hi0[3]+=hi1[3];
  lo2[0]+=lo3[0]; lo2[1]+=lo3[1]; lo2[2]+=lo3[2]; lo2[3]+=lo3[3];
  hi2[0]+=hi3[0]; hi2[1]+=hi3[1]; hi2[2]+=hi3[2]; hi2[3]+=hi3[3];
  lo0[0]+=lo2[0]; lo0[1]+=lo2[1]; lo0[2]+=lo2[2]; lo0[3]+=lo2[3];
  hi0[0]+=hi2[0]; hi0[1]+=hi2[1]; hi0[2]+=hi2[2]; hi0[3]+=hi2[3];
  olo = lo0; ohi = hi0;
}

// -------- standalone aggregation: 16 nodes/block --------
__global__ __launch_bounds__(256) void k_agg(const h16* __restrict__ XW,
    const int* __restrict__ offs, const int* __restrict__ csr,
    const float* __restrict__ dinv, const float* __restrict__ bias,
    h16* __restrict__ out, int n) {
  int gid = threadIdx.x >> 4;
  int lane = threadIdx.x & 15;
  int node = blockIdx.x * 16 + gid;
  if (node >= n) return;
  int f0 = lane * 8;
  f32x4 lo, hi;
  gather_row8(XW, offs, csr, node, f0, lo, hi);
  float d = dinv[node];
  float4 b0 = *(const float4*)&bias[f0];
  float4 b1 = *(const float4*)&bias[f0 + 4];
  h16x8 o;
  o[0] = (h16)fmaxf(lo[0] * d + b0.x, 0.f);
  o[1] = (h16)fmaxf(lo[1] * d + b0.y, 0.f);
  o[2] = (h16)fmaxf(lo[2] * d + b0.z, 0.f);
  o[3] = (h16)fmaxf(lo[3] * d + b0.w, 0.f);
  o[4] = (h16)fmaxf(hi[0] * d + b1.x, 0.f);
  o[5] = (h16)fmaxf(hi[1] * d + b1.y, 0.f);
  o[6] = (h16)fmaxf(hi[2] * d + b1.z, 0.f);
  o[7] = (h16)fmaxf(hi[3] * d + b1.w, 0.f);
  *(h16x8*)&out[(size_t)node * FEAT + f0] = o;
}

// -------- fused aggregation + pvec --------
__global__ __launch_bounds__(256) void k_agg_pvec(const h16* __restrict__ XW,
    const int* __restrict__ offs, const int* __restrict__ csr,
    const float* __restrict__ dinv, const float* __restrict__ bias,
    const float* __restrict__ fcw, const float* __restrict__ fcb,
    float* __restrict__ p, int n) {
  int gid = threadIdx.x >> 4;
  int lane = threadIdx.x & 15;
  int node = blockIdx.x * 16 + gid;
  if (node >= n) return;
  int f0 = lane * 8;
  f32x4 lo, hi;
  gather_row8(XW, offs, csr, node, f0, lo, hi);
  float d = dinv[node];
  float4 b0 = *(const float4*)&bias[f0];
  float4 b1 = *(const float4*)&bias[f0 + 4];
  float4 w0 = *(const float4*)&fcw[f0];
  float4 w1 = *(const float4*)&fcw[f0 + 4];
  float acc = fmaxf(lo[0] * d + b0.x, 0.f) * w0.x
            + fmaxf(lo[1] * d + b0.y, 0.f) * w0.y
            + fmaxf(lo[2] * d + b0.z, 0.f) * w0.z
            + fmaxf(lo[3] * d + b0.w, 0.f) * w0.w
            + fmaxf(hi[0] * d + b1.x, 0.f) * w1.x
            + fmaxf(hi[1] * d + b1.y, 0.f) * w1.y
            + fmaxf(hi[2] * d + b1.z, 0.f) * w1.z
            + fmaxf(hi[3] * d + b1.w, 0.f) * w1.w;
#pragma unroll
  for (int off = 8; off > 0; off >>= 1) acc += __shfl_xor(acc, off, 16);
  if (lane == 0) p[node] = 1.0f / (1.0f + expf(-(acc + fcb[0])));
}

// -------- fused final aggregation + mean-pool partial (per graph,slice) --------
__global__ __launch_bounds__(256) void k_agg_pool(const h16* __restrict__ XW,
    const int* __restrict__ offs, const int* __restrict__ csr,
    const float* __restrict__ dinv, const float* __restrict__ bias,
    const int* __restrict__ batch, float* __restrict__ part, int n) {
  int g = blockIdx.x / PSL2;
  int s = blockIdx.x % PSL2;
  int lo_ = 0, hi_ = n;
  while (lo_ < hi_) { int m = (lo_ + hi_) >> 1; if (batch[m] < g) lo_ = m + 1; else hi_ = m; }
  int start = lo_;
  hi_ = n;
  while (lo_ < hi_) { int m = (lo_ + hi_) >> 1; if (batch[m] <= g) lo_ = m + 1; else hi_ = m; }
  int end = lo_;
  int len = end - start;
  int per = (len + PSL2 - 1) / PSL2;
  int r0 = start + s * per;
  int r1 = min(r0 + per, end);
  int gid = threadIdx.x >> 4;
  int lane = threadIdx.x & 15;
  int f0 = lane * 8;
  float4 b0 = *(const float4*)&bias[f0];
  float4 b1 = *(const float4*)&bias[f0 + 4];
  f32x4 plo = {0,0,0,0}, phi = {0,0,0,0};
  for (int node = r0 + gid; node < r1; node += 16) {
    f32x4 lo, hi;
    gather_row8(XW, offs, csr, node, f0, lo, hi);
    float d = dinv[node];
    plo[0] += fmaxf(lo[0] * d + b0.x, 0.f);
    plo[1] += fmaxf(lo[1] * d + b0.y, 0.f);
    plo[2] += fmaxf(lo[2] * d + b0.z, 0.f);
    plo[3] += fmaxf(lo[3] * d + b0.w, 0.f);
    phi[0] += fmaxf(hi[0] * d + b1.x, 0.f);
    phi[1] += fmaxf(hi[1] * d + b1.y, 0.f);
    phi[2] += fmaxf(hi[2] * d + b1.z, 0.f);
    phi[3] += fmaxf(hi[3] * d + b1.w, 0.f);
  }
  __shared__ float lds[16 * FEAT];
  *(f32x4*)&lds[gid * FEAT + f0] = plo;
  *(f32x4*)&lds[gid * FEAT + f0 + 4] = phi;
  __syncthreads();
  if (threadIdx.x < FEAT) {
    int f = threadIdx.x;
    float t = 0.f;
#pragma unroll
    for (int q = 0; q < 16; ++q) t += lds[q * FEAT + f];
    part[(size_t)blockIdx.x * FEAT + f] = t;
  }
}

// ---------- pool finalize: reduce slices, divide by count ----------
__global__ __launch_bounds__(128) void k_pool_fin(const float* __restrict__ part,
    const int* __restrict__ batch, float* __restrict__ out, int n) {
  int g = blockIdx.x;
  int lo = 0, hi = n;
  while (lo < hi) { int m = (lo + hi) >> 1; if (batch[m] < g) lo = m + 1; else hi = m; }
  int start = lo;
  hi = n;
  while (lo < hi) { int m = (lo + hi) >> 1; if (batch[m] <= g) lo = m + 1; else hi = m; }
  int len = lo - start;
  int f = threadIdx.x;
  float tot = 0.f;
#pragma unroll
  for (int s = 0; s < PSL2; ++s) tot += part[(size_t)(g * PSL2 + s) * FEAT + f];
  out[(size_t)g * FEAT + f] = tot / fmaxf((float)len, 1.0f);
}

// ---------------- LDS-free MFMA GEMM ----------------
// A fragments loaded directly from global (each X element read once per block);
// B fragments from WT (32 KB, L2-hot, reused by all blocks). No LDS, no barrier.
__device__ inline h16x8 load8(const float* p) {
  float4 a = *(const float4*)p, b = *(const float4*)(p + 4);
  h16x8 o;
  o[0] = (h16)a.x; o[1] = (h16)a.y; o[2] = (h16)a.z; o[3] = (h16)a.w;
  o[4] = (h16)b.x; o[5] = (h16)b.y; o[6] = (h16)b.z; o[7] = (h16)b.w;
  return o;
}
__device__ inline h16x8 load8(const h16* p) { return *(const h16x8*)p; }

template <typename TI>
__global__ __launch_bounds__(256) void k_gemm_mfma(const TI* __restrict__ X,
    const h16* __restrict__ WT, const float* __restrict__ s1, const float* __restrict__ s2,
    h16* __restrict__ Y, int n) {
  int tid = threadIdx.x;
  int row0 = blockIdx.x * 128;
  int w = tid >> 6, l = tid & 63;
  int lr = l & 15, lq = l >> 4;
  // A fragments: rows w*32+m*16+lr, k = s*32 + lq*8 (16B contiguous)
  h16x8 af[2][4];
#pragma unroll
  for (int m = 0; m < 2; ++m)
#pragma unroll
    for (int s = 0; s < 4; ++s) {
      int r = row0 + w * 32 + m * 16 + lr;
      r = min(r, n - 1);               // clamp: garbage stays in its own output row
      af[m][s] = load8(&X[(size_t)r * FEAT + s * 32 + lq * 8]);
    }
  f32x4 acc[2][8];
#pragma unroll
  for (int m = 0; m < 2; ++m)
#pragma unroll
    for (int nn = 0; nn < 8; ++nn) acc[m][nn] = (f32x4){0.f, 0.f, 0.f, 0.f};
#pragma unroll
  for (int nn = 0; nn < 8; ++nn) {
#pragma unroll
    for (int s = 0; s < 4; ++s) {
      h16x8 bf = *(const h16x8*)&WT[(size_t)(nn * 16 + lr) * FEAT + s * 32 + lq * 8];
      acc[0][nn] = __builtin_amdgcn_mfma_f32_16x16x32_f16(af[0][s], bf, acc[0][nn], 0, 0, 0);
      acc[1][nn] = __builtin_amdgcn_mfma_f32_16x16x32_f16(af[1][s], bf, acc[1][nn], 0, 0, 0);
    }
  }
#pragma unroll
  for (int m = 0; m < 2; ++m) {
#pragma unroll
    for (int r = 0; r < 4; ++r) {
      int grow = row0 + w * 32 + m * 16 + lq * 4 + r;
      if (grow < n) {
        float sc = 1.0f;
        if (s1) sc = s1[grow];
        if (s2) sc *= s2[grow];
#pragma unroll
        for (int nn = 0; nn < 8; ++nn)
          Y[(size_t)grow * FEAT + nn * 16 + lr] = (h16)(acc[m][nn][r] * sc);
      }
    }
  }
}

extern "C" void kernel_launch(void* const* d_in, const int* in_sizes, int n_in,
                              void* d_out, int out_size, void* d_ws, size_t ws_size,
                              hipStream_t stream) {
  const float* x_H    = (const float*)d_in[0];
  const int*   ei_H   = (const int*)d_in[1];
  const float* x_G    = (const float*)d_in[2];
  const int*   ei_G   = (const int*)d_in[3];
  const int*   bat_H  = (const int*)d_in[4];
  const int*   bat_G  = (const int*)d_in[5];
  const float* sel_W1 = (const float*)d_in[6];
  const float* sel_b1 = (const float*)d_in[7];
  const float* sel_W2 = (const float*)d_in[8];
  const float* sel_b2 = (const float*)d_in[9];
  const float* sel_fcw = (const float*)d_in[10];
  const float* sel_fcb = (const float*)d_in[11];
  const float* emb_W1 = (const float*)d_in[12];
  const float* emb_b1 = (const float*)d_in[13];
  const float* emb_W2 = (const float*)d_in[14];
  const float* emb_b2 = (const float*)d_in[15];

  const int N = in_sizes[0] / FEAT;
  const int E = in_sizes[1] / 2;
  const int NG = 64;
  const int NB = (N + 127) >> BSHIFT;

  float* out = (float*)d_out;
  float* hF = out;
  float* hG = out + NG * FEAT;
  float* p  = out + 2 * NG * FEAT;

  char* ws = (char*)d_ws;
  size_t off = 0;
  auto alloc = [&](size_t bytes) -> void* {
    void* ptr = (void*)(ws + off);
    off += (bytes + 511) & ~(size_t)511;
    return ptr;
  };
  const size_t SZH = (size_t)N * FEAT * sizeof(h16);          // 25.6 MB
  const size_t SZP = (size_t)NB * CAP * sizeof(unsigned int); // 12.8 MB
  const size_t SZB = SZH > SZP ? SZH : SZP;
  h16* A       = (h16*)alloc(SZB);
  h16* B       = (h16*)alloc(SZB);
  h16* C       = (h16*)alloc(SZH);
  h16* x16H    = (h16*)alloc(SZH);
  float* dinvH = (float*)alloc((size_t)N * 4);
  float* dinvG = (float*)alloc((size_t)N * 4);
  int*  offsH  = (int*)alloc((size_t)(N + 1) * 4);
  int*  offsG  = (int*)alloc((size_t)(N + 1) * 4);
  int*  csrH   = (int*)alloc((size_t)E * 4);
  int*  csrG   = (int*)alloc((size_t)E * 4);
  int*  gcurH  = (int*)alloc((size_t)NB * 4);
  int*  gcurG  = (int*)alloc((size_t)NB * 4);
  int*  boffsH = (int*)alloc((size_t)(NB + 1) * 4);
  int*  boffsG = (int*)alloc((size_t)(NB + 1) * 4);
  float* part  = (float*)alloc((size_t)NG * PSL2 * FEAT * 4); // 2 MB
  h16* wtSel1  = (h16*)alloc((size_t)FEAT * FEAT * 2);
  h16* wtSel2  = (h16*)alloc((size_t)FEAT * FEAT * 2);
  h16* wtEmb1  = (h16*)alloc((size_t)FEAT * FEAT * 2);
  h16* wtEmb2  = (h16*)alloc((size_t)FEAT * FEAT * 2);
  (void)ws_size;

  unsigned int* pairH = (unsigned int*)A;
  unsigned int* pairG = (unsigned int*)B;

  const int gGemm = (N + 127) / 128;
  const int gAgg  = (N + 15) / 16;

  // ---- weight prep + x_H fp16 convert ----
  k_wprep<<<64, 256, 0, stream>>>(sel_W1, wtSel1);
  k_wprep<<<64, 256, 0, stream>>>(sel_W2, wtSel2);
  k_wprep<<<64, 256, 0, stream>>>(emb_W1, wtEmb1);
  k_wprep<<<64, 256, 0, stream>>>(emb_W2, wtEmb2);
  k_cvt<<<(N * FEAT / 8 + 255) / 256, 256, 0, stream>>>(x_H, x16H, N * FEAT / 8);

  // ---- build CSR for H and G ----
  hipMemsetAsync(gcurH, 0, (size_t)NB * 4, stream);
  hipMemsetAsync(gcurG, 0, (size_t)NB * 4, stream);
  k_part<<<256, 256, 0, stream>>>(ei_H, pairH, gcurH, E, NB);
  k_part<<<256, 256, 0, stream>>>(ei_G, pairG, gcurG, E, NB);
  k_bscan<<<1, 1024, 0, stream>>>(gcurH, boffsH, offsH, NB, N, E);
  k_bscan<<<1, 1024, 0, stream>>>(gcurG, boffsG, offsG, NB, N, E);
  k_bucket<<<NB, 256, 0, stream>>>(pairH, gcurH, boffsH, csrH, offsH, dinvH, N);
  k_bucket<<<NB, 256, 0, stream>>>(pairG, gcurG, boffsG, csrG, offsG, dinvG, N);

  // ---- selector: gemm1 -> agg -> gemm2 -> fused agg+pvec ----
  k_gemm_mfma<h16><<<gGemm, 256, 0, stream>>>(x16H, wtSel1, dinvH, nullptr, A, N);
  k_agg<<<gAgg, 256, 0, stream>>>(A, offsH, csrH, dinvH, sel_b1, B, N);
  k_gemm_mfma<h16><<<gGemm, 256, 0, stream>>>(B, wtSel2, dinvH, nullptr, C, N);
  k_agg_pvec<<<gAgg, 256, 0, stream>>>(C, offsH, csrH, dinvH, sel_b2, sel_fcw, sel_fcb, p, N);

  // ---- F branch: gemm1 -> agg -> gemm2 -> fused agg+pool ----
  k_gemm_mfma<h16><<<gGemm, 256, 0, stream>>>(x16H, wtEmb1, dinvH, p, A, N);
  k_agg<<<gAgg, 256, 0, stream>>>(A, offsH, csrH, dinvH, emb_b1, B, N);
  k_gemm_mfma<h16><<<gGemm, 256, 0, stream>>>(B, wtEmb2, dinvH, nullptr, C, N);
  k_agg_pool<<<NG * PSL2, 256, 0, stream>>>(C, offsH, csrH, dinvH, emb_b2, bat_H, part, N);
  k_pool_fin<<<NG, 128, 0, stream>>>(part, bat_H, hF, N);

  // ---- G branch ----
  k_gemm_mfma<float><<<gGemm, 256, 0, stream>>>(x_G, wtEmb1, dinvG, nullptr, A, N);
  k_agg<<<gAgg, 256, 0, stream>>>(A, offsG, csrG, dinvG, emb_b1, B, N);
  k_gemm_mfma<h16><<<gGemm, 256, 0, stream>>>(B, wtEmb2, dinvG, nullptr, C, N);
  k_agg_pool<<<NG * PSL2, 256, 0, stream>>>(C, offsG, csrG, dinvG, emb_b2, bat_G, part, N);
  k_pool_fin<<<NG, 128, 0, stream>>>(part, bat_G, hG, N);
}

// Round 13
// 644.943 us; speedup vs baseline: 1.1636x; 1.1636x over previous
//
#include <hip/hip_runtime.h>
#include <cstdint>
#include <cstddef>

#define FEAT 128
#define PSL2 32           // pool slices for fused agg+pool
#define BSHIFT 7          // 128 nodes per bucket
#define CAP 4096          // bucket capacity (mean 2048 for E=1.6M, N=100k)

typedef _Float16 h16;
typedef __attribute__((ext_vector_type(8))) _Float16 h16x8;
typedef __attribute__((ext_vector_type(4))) float f32x4;

// ---------- fp32 -> fp16 bulk convert (8 elems/thread) ----------
__global__ __launch_bounds__(256) void k_cvt(const float* __restrict__ X,
    h16* __restrict__ Y, int nv) {
  int i = blockIdx.x * 256 + threadIdx.x;
  if (i < nv) {
    const float* p = X + (size_t)i * 8;
    float4 a = *(const float4*)p, b = *(const float4*)(p + 4);
    h16x8 o;
    o[0] = (h16)a.x; o[1] = (h16)a.y; o[2] = (h16)a.z; o[3] = (h16)a.w;
    o[4] = (h16)b.x; o[5] = (h16)b.y; o[6] = (h16)b.z; o[7] = (h16)b.w;
    *(h16x8*)&Y[(size_t)i * 8] = o;
  }
}

// ---------- pass 1: block-level radix partition; packed (src<<7 | dstLocal) ----------
__global__ __launch_bounds__(256) void k_part(const int* __restrict__ ei,
    unsigned int* __restrict__ pair, int* __restrict__ gcur, int E, int nb) {
  __shared__ int cnt[1024];
  __shared__ int base[1024];
  int per = (E + gridDim.x - 1) / gridDim.x;
  int e0 = blockIdx.x * per;
  int e1 = min(e0 + per, E);
  for (int i = threadIdx.x; i < nb; i += 256) cnt[i] = 0;
  __syncthreads();
  for (int e = e0 + threadIdx.x; e < e1; e += 256)
    atomicAdd(&cnt[ei[E + e] >> BSHIFT], 1);
  __syncthreads();
  for (int i = threadIdx.x; i < nb; i += 256) {
    int c = cnt[i];
    base[i] = c ? atomicAdd(&gcur[i], c) : 0;
    cnt[i] = 0;   // reuse as intra-block cursor
  }
  __syncthreads();
  for (int e = e0 + threadIdx.x; e < e1; e += 256) {
    int src = ei[e];
    int dst = ei[E + e];
    int b = dst >> BSHIFT;
    int pos = base[b] + atomicAdd(&cnt[b], 1);
    if (pos < CAP) pair[(size_t)b * CAP + pos] = ((unsigned)src << BSHIFT) | (unsigned)(dst & 127);
  }
}

// ---------- small scan over bucket counts -> bucket offsets ----------
__global__ __launch_bounds__(1024) void k_bscan(const int* __restrict__ cnt,
    int* __restrict__ boffs, int* __restrict__ offs, int nb, int N, int E) {
  __shared__ int wsum[16];
  __shared__ int carry;
  int tid = threadIdx.x;
  int lane = tid & 63;
  int wid = tid >> 6;
  if (tid == 0) carry = 0;
  for (int base = 0; base < nb; base += 1024) {
    __syncthreads();
    int c0 = carry;
    int i = base + tid;
    int v = (i < nb) ? cnt[i] : 0;
    int x = v;
#pragma unroll
    for (int off = 1; off < 64; off <<= 1) {
      int t = __shfl_up(x, off);
      if (lane >= off) x += t;
    }
    if (lane == 63) wsum[wid] = x;
    __syncthreads();
    if (wid == 0) {
      int t = (lane < 16) ? wsum[lane] : 0;
#pragma unroll
      for (int off = 1; off < 16; off <<= 1) {
        int u = __shfl_up(t, off);
        if (lane >= off) t += u;
      }
      if (lane < 16) wsum[lane] = t;
    }
    __syncthreads();
    int wex = (wid == 0) ? 0 : wsum[wid - 1];
    int o = c0 + wex + (x - v);
    if (i < nb) boffs[i] = o;
    int total = wsum[15];
    __syncthreads();
    if (tid == 0) carry = c0 + total;
  }
  __syncthreads();
  if (tid == 0) { boffs[nb] = carry; offs[N] = E; }
}

// ---------- pass 2: per-bucket count/scan/scatter -> csr, offs, dinv ----------
__global__ __launch_bounds__(256) void k_bucket(const unsigned int* __restrict__ pair,
    const int* __restrict__ bcnt, const int* __restrict__ boffs,
    int* __restrict__ csr, int* __restrict__ offs, float* __restrict__ dinv,
    int N) {
  int b = blockIdx.x;
  int m = min(bcnt[b], CAP);
  __shared__ int cnt[128];
  __shared__ int noff[128];
  __shared__ int w0tot;
  if (threadIdx.x < 128) cnt[threadIdx.x] = 0;
  __syncthreads();
  const unsigned int* p = pair + (size_t)b * CAP;
  for (int i = threadIdx.x; i < m; i += 256)
    atomicAdd(&cnt[p[i] & 127u], 1);
  __syncthreads();
  int v = 0, x = 0;
  int lane = threadIdx.x & 63, w = threadIdx.x >> 6;
  if (threadIdx.x < 128) {
    v = cnt[threadIdx.x];
    x = v;
#pragma unroll
    for (int o = 1; o < 64; o <<= 1) {
      int t = __shfl_up(x, o);
      if (lane >= o) x += t;
    }
    if (threadIdx.x == 63) w0tot = x;
  }
  __syncthreads();
  int cbase = boffs[b];
  if (threadIdx.x < 128) {
    int ex = x - v + ((w == 1) ? w0tot : 0);
    int g = (b << BSHIFT) + threadIdx.x;
    if (g < N) {
      offs[g] = cbase + ex;
      dinv[g] = 1.0f / sqrtf((float)v + 1.0f);
    }
    noff[threadIdx.x] = ex;
    cnt[threadIdx.x] = 0;
  }
  __syncthreads();
  for (int i = threadIdx.x; i < m; i += 256) {
    unsigned pk = p[i];
    int d = pk & 127u;
    int pos = cbase + noff[d] + atomicAdd(&cnt[d], 1);
    csr[pos] = (int)(pk >> BSHIFT);
  }
}

// ---------- W prep: fp32 [k][col] -> fp16 transposed [col][k] ----------
__global__ __launch_bounds__(256) void k_wprep(const float* __restrict__ W,
    h16* __restrict__ WT) {
  int i = blockIdx.x * 256 + threadIdx.x;
  int k = i >> 7, c = i & 127;
  WT[c * FEAT + k] = (h16)W[(size_t)k * FEAT + c];
}

// ---------- gather core: 16 lanes/node, 16B (h16x8) per lane ----------
__device__ inline void acc8(f32x4& lo, f32x4& hi, h16x8 v) {
  lo[0] += (float)v[0]; lo[1] += (float)v[1]; lo[2] += (float)v[2]; lo[3] += (float)v[3];
  hi[0] += (float)v[4]; hi[1] += (float)v[5]; hi[2] += (float)v[6]; hi[3] += (float)v[7];
}

__device__ inline void gather_row8(const h16* __restrict__ XW,
    const int* __restrict__ offs, const int* __restrict__ csr,
    int node, int f0, f32x4& olo, f32x4& ohi) {
  f32x4 lo0 = {0,0,0,0}, hi0 = {0,0,0,0};
  f32x4 lo1 = {0,0,0,0}, hi1 = {0,0,0,0};
  f32x4 lo2 = {0,0,0,0}, hi2 = {0,0,0,0};
  f32x4 lo3 = {0,0,0,0}, hi3 = {0,0,0,0};
  h16x8 sv = *(const h16x8*)&XW[(size_t)node * FEAT + f0];   // self term
  acc8(lo0, hi0, sv);
  int s = offs[node], e = offs[node + 1];
  int i = s;
  for (; i + 8 <= e; i += 8) {
    int s0 = csr[i + 0], s1 = csr[i + 1], s2 = csr[i + 2], s3 = csr[i + 3];
    int s4 = csr[i + 4], s5 = csr[i + 5], s6 = csr[i + 6], s7 = csr[i + 7];
    h16x8 v0 = *(const h16x8*)&XW[(size_t)s0 * FEAT + f0];
    h16x8 v1 = *(const h16x8*)&XW[(size_t)s1 * FEAT + f0];
    h16x8 v2 = *(const h16x8*)&XW[(size_t)s2 * FEAT + f0];
    h16x8 v3 = *(const h16x8*)&XW[(size_t)s3 * FEAT + f0];
    h16x8 v4 = *(const h16x8*)&XW[(size_t)s4 * FEAT + f0];
    h16x8 v5 = *(const h16x8*)&XW[(size_t)s5 * FEAT + f0];
    h16x8 v6 = *(const h16x8*)&XW[(size_t)s6 * FEAT + f0];
    h16x8 v7 = *(const h16x8*)&XW[(size_t)s7 * FEAT + f0];
    acc8(lo0, hi0, v0); acc8(lo1, hi1, v1);
    acc8(lo2, hi2, v2); acc8(lo3, hi3, v3);
    acc8(lo0, hi0, v4); acc8(lo1, hi1, v5);
    acc8(lo2, hi2, v6); acc8(lo3, hi3, v7);
  }
  if (i + 4 <= e) {
    int s0 = csr[i + 0], s1 = csr[i + 1], s2 = csr[i + 2], s3 = csr[i + 3];
    h16x8 v0 = *(const h16x8*)&XW[(size_t)s0 * FEAT + f0];
    h16x8 v1 = *(const h16x8*)&XW[(size_t)s1 * FEAT + f0];
    h16x8 v2 = *(const h16x8*)&XW[(size_t)s2 * FEAT + f0];
    h16x8 v3 = *(const h16x8*)&XW[(size_t)s3 * FEAT + f0];
    acc8(lo0, hi0, v0); acc8(lo1, hi1, v1);
    acc8(lo2, hi2, v2); acc8(lo3, hi3, v3);
    i += 4;
  }
  for (; i < e; ++i) {
    int s0 = csr[i];
    h16x8 v0 = *(const h16x8*)&XW[(size_t)s0 * FEAT + f0];
    acc8(lo1, hi1, v0);
  }
  lo0[0]+=lo1[0]; lo0[1]+=lo1[1]; lo0[2]+=lo1[2]; lo0[3]+=lo1[3];
  hi0[0]+=hi1[0]; hi0[1]+=hi1[1]; hi0[2]+=hi1[2]; hi0[3]+=hi1[3];
  lo2[0]+=lo3[0]; lo2[1]+=lo3[1]; lo2[2]+=lo3[2]; lo2[3]+=lo3[3];
  hi2[0]+=hi3[0]; hi2[1]+=hi3[1]; hi2[2]+=hi3[2]; hi2[3]+=hi3[3];
  lo0[0]+=lo2[0]; lo0[1]+=lo2[1]; lo0[2]+=lo2[2]; lo0[3]+=lo2[3];
  hi0[0]+=hi2[0]; hi0[1]+=hi2[1]; hi0[2]+=hi2[2]; hi0[3]+=hi2[3];
  olo = lo0; ohi = hi0;
}

// -------- standalone aggregation: 16 nodes/block --------
__global__ __launch_bounds__(256) void k_agg(const h16* __restrict__ XW,
    const int* __restrict__ offs, const int* __restrict__ csr,
    const float* __restrict__ dinv, const float* __restrict__ bias,
    h16* __restrict__ out, int n) {
  int gid = threadIdx.x >> 4;
  int lane = threadIdx.x & 15;
  int node = blockIdx.x * 16 + gid;
  if (node >= n) return;
  int f0 = lane * 8;
  f32x4 lo, hi;
  gather_row8(XW, offs, csr, node, f0, lo, hi);
  float d = dinv[node];
  float4 b0 = *(const float4*)&bias[f0];
  float4 b1 = *(const float4*)&bias[f0 + 4];
  h16x8 o;
  o[0] = (h16)fmaxf(lo[0] * d + b0.x, 0.f);
  o[1] = (h16)fmaxf(lo[1] * d + b0.y, 0.f);
  o[2] = (h16)fmaxf(lo[2] * d + b0.z, 0.f);
  o[3] = (h16)fmaxf(lo[3] * d + b0.w, 0.f);
  o[4] = (h16)fmaxf(hi[0] * d + b1.x, 0.f);
  o[5] = (h16)fmaxf(hi[1] * d + b1.y, 0.f);
  o[6] = (h16)fmaxf(hi[2] * d + b1.z, 0.f);
  o[7] = (h16)fmaxf(hi[3] * d + b1.w, 0.f);
  *(h16x8*)&out[(size_t)node * FEAT + f0] = o;
}

// -------- fused aggregation + pvec --------
__global__ __launch_bounds__(256) void k_agg_pvec(const h16* __restrict__ XW,
    const int* __restrict__ offs, const int* __restrict__ csr,
    const float* __restrict__ dinv, const float* __restrict__ bias,
    const float* __restrict__ fcw, const float* __restrict__ fcb,
    float* __restrict__ p, int n) {
  int gid = threadIdx.x >> 4;
  int lane = threadIdx.x & 15;
  int node = blockIdx.x * 16 + gid;
  if (node >= n) return;
  int f0 = lane * 8;
  f32x4 lo, hi;
  gather_row8(XW, offs, csr, node, f0, lo, hi);
  float d = dinv[node];
  float4 b0 = *(const float4*)&bias[f0];
  float4 b1 = *(const float4*)&bias[f0 + 4];
  float4 w0 = *(const float4*)&fcw[f0];
  float4 w1 = *(const float4*)&fcw[f0 + 4];
  float acc = fmaxf(lo[0] * d + b0.x, 0.f) * w0.x
            + fmaxf(lo[1] * d + b0.y, 0.f) * w0.y
            + fmaxf(lo[2] * d + b0.z, 0.f) * w0.z
            + fmaxf(lo[3] * d + b0.w, 0.f) * w0.w
            + fmaxf(hi[0] * d + b1.x, 0.f) * w1.x
            + fmaxf(hi[1] * d + b1.y, 0.f) * w1.y
            + fmaxf(hi[2] * d + b1.z, 0.f) * w1.z
            + fmaxf(hi[3] * d + b1.w, 0.f) * w1.w;
#pragma unroll
  for (int off = 8; off > 0; off >>= 1) acc += __shfl_xor(acc, off, 16);
  if (lane == 0) p[node] = 1.0f / (1.0f + expf(-(acc + fcb[0])));
}

// -------- fused final aggregation + mean-pool partial (per graph,slice) --------
__global__ __launch_bounds__(256) void k_agg_pool(const h16* __restrict__ XW,
    const int* __restrict__ offs, const int* __restrict__ csr,
    const float* __restrict__ dinv, const float* __restrict__ bias,
    const int* __restrict__ batch, float* __restrict__ part, int n) {
  int g = blockIdx.x / PSL2;
  int s = blockIdx.x % PSL2;
  int lo_ = 0, hi_ = n;
  while (lo_ < hi_) { int m = (lo_ + hi_) >> 1; if (batch[m] < g) lo_ = m + 1; else hi_ = m; }
  int start = lo_;
  hi_ = n;
  while (lo_ < hi_) { int m = (lo_ + hi_) >> 1; if (batch[m] <= g) lo_ = m + 1; else hi_ = m; }
  int end = lo_;
  int len = end - start;
  int per = (len + PSL2 - 1) / PSL2;
  int r0 = start + s * per;
  int r1 = min(r0 + per, end);
  int gid = threadIdx.x >> 4;
  int lane = threadIdx.x & 15;
  int f0 = lane * 8;
  float4 b0 = *(const float4*)&bias[f0];
  float4 b1 = *(const float4*)&bias[f0 + 4];
  f32x4 plo = {0,0,0,0}, phi = {0,0,0,0};
  for (int node = r0 + gid; node < r1; node += 16) {
    f32x4 lo, hi;
    gather_row8(XW, offs, csr, node, f0, lo, hi);
    float d = dinv[node];
    plo[0] += fmaxf(lo[0] * d + b0.x, 0.f);
    plo[1] += fmaxf(lo[1] * d + b0.y, 0.f);
    plo[2] += fmaxf(lo[2] * d + b0.z, 0.f);
    plo[3] += fmaxf(lo[3] * d + b0.w, 0.f);
    phi[0] += fmaxf(hi[0] * d + b1.x, 0.f);
    phi[1] += fmaxf(hi[1] * d + b1.y, 0.f);
    phi[2] += fmaxf(hi[2] * d + b1.z, 0.f);
    phi[3] += fmaxf(hi[3] * d + b1.w, 0.f);
  }
  __shared__ float lds[16 * FEAT];
  *(f32x4*)&lds[gid * FEAT + f0] = plo;
  *(f32x4*)&lds[gid * FEAT + f0 + 4] = phi;
  __syncthreads();
  if (threadIdx.x < FEAT) {
    int f = threadIdx.x;
    float t = 0.f;
#pragma unroll
    for (int q = 0; q < 16; ++q) t += lds[q * FEAT + f];
    part[(size_t)blockIdx.x * FEAT + f] = t;
  }
}

// ---------- pool finalize: reduce slices, divide by count ----------
__global__ __launch_bounds__(128) void k_pool_fin(const float* __restrict__ part,
    const int* __restrict__ batch, float* __restrict__ out, int n) {
  int g = blockIdx.x;
  int lo = 0, hi = n;
  while (lo < hi) { int m = (lo + hi) >> 1; if (batch[m] < g) lo = m + 1; else hi = m; }
  int start = lo;
  hi = n;
  while (lo < hi) { int m = (lo + hi) >> 1; if (batch[m] <= g) lo = m + 1; else hi = m; }
  int len = lo - start;
  int f = threadIdx.x;
  float tot = 0.f;
#pragma unroll
  for (int s = 0; s < PSL2; ++s) tot += part[(size_t)(g * PSL2 + s) * FEAT + f];
  out[(size_t)g * FEAT + f] = tot / fmaxf((float)len, 1.0f);
}

// ---------------- MFMA GEMM (LDS-staged) ----------------
__device__ inline h16x8 load8(const float* p) {
  float4 a = *(const float4*)p, b = *(const float4*)(p + 4);
  h16x8 o;
  o[0] = (h16)a.x; o[1] = (h16)a.y; o[2] = (h16)a.z; o[3] = (h16)a.w;
  o[4] = (h16)b.x; o[5] = (h16)b.y; o[6] = (h16)b.z; o[7] = (h16)b.w;
  return o;
}
__device__ inline h16x8 load8(const h16* p) { return *(const h16x8*)p; }

template <typename TI>
__global__ __launch_bounds__(256) void k_gemm_mfma(const TI* __restrict__ X,
    const h16* __restrict__ WT, const float* __restrict__ s1, const float* __restrict__ s2,
    h16* __restrict__ Y, int n) {
  __shared__ __align__(16) h16 lA[128 * FEAT];
  __shared__ __align__(16) h16 lB[128 * FEAT];
  int tid = threadIdx.x;
  int row0 = blockIdx.x * 128;
#pragma unroll
  for (int i = 0; i < 8; ++i) {
    int c = tid + i * 256;
    int r = c >> 4, kc = c & 15;
    int grow = row0 + r;
    h16x8 v;
#pragma unroll
    for (int j = 0; j < 8; ++j) v[j] = (h16)0.f;
    if (grow < n) v = load8(&X[(size_t)grow * FEAT + kc * 8]);
    int byte = r * 256 + ((kc * 16) ^ ((r & 7) << 4));
    *(h16x8*)((char*)lA + byte) = v;
  }
#pragma unroll
  for (int i = 0; i < 8; ++i) {
    int c = tid + i * 256;
    int col = c >> 4, kc = c & 15;
    h16x8 v = *(const h16x8*)&WT[col * FEAT + kc * 8];
    int byte = col * 256 + ((kc * 16) ^ ((col & 7) << 4));
    *(h16x8*)((char*)lB + byte) = v;
  }
  __syncthreads();
  int w = tid >> 6, l = tid & 63;
  int lr = l & 15, lq = l >> 4;
  h16x8 af[2][4];
#pragma unroll
  for (int m = 0; m < 2; ++m)
#pragma unroll
    for (int s = 0; s < 4; ++s) {
      int r = w * 32 + m * 16 + lr;
      int k2 = (s * 32 + lq * 8) * 2;
      int byte = r * 256 + (k2 ^ ((r & 7) << 4));
      af[m][s] = *(const h16x8*)((const char*)lA + byte);
    }
  f32x4 acc[2][8];
#pragma unroll
  for (int m = 0; m < 2; ++m)
#pragma unroll
    for (int nn = 0; nn < 8; ++nn) acc[m][nn] = (f32x4){0.f, 0.f, 0.f, 0.f};
#pragma unroll
  for (int nn = 0; nn < 8; ++nn) {
#pragma unroll
    for (int s = 0; s < 4; ++s) {
      int col = nn * 16 + lr;
      int k2 = (s * 32 + lq * 8) * 2;
      int byte = col * 256 + (k2 ^ ((col & 7) << 4));
      h16x8 bf = *(const h16x8*)((const char*)lB + byte);
      acc[0][nn] = __builtin_amdgcn_mfma_f32_16x16x32_f16(af[0][s], bf, acc[0][nn], 0, 0, 0);
      acc[1][nn] = __builtin_amdgcn_mfma_f32_16x16x32_f16(af[1][s], bf, acc[1][nn], 0, 0, 0);
    }
  }
#pragma unroll
  for (int m = 0; m < 2; ++m) {
#pragma unroll
    for (int r = 0; r < 4; ++r) {
      int grow = row0 + w * 32 + m * 16 + lq * 4 + r;
      if (grow < n) {
        float sc = 1.0f;
        if (s1) sc = s1[grow];
        if (s2) sc *= s2[grow];
#pragma unroll
        for (int nn = 0; nn < 8; ++nn)
          Y[(size_t)grow * FEAT + nn * 16 + lr] = (h16)(acc[m][nn][r] * sc);
      }
    }
  }
}

extern "C" void kernel_launch(void* const* d_in, const int* in_sizes, int n_in,
                              void* d_out, int out_size, void* d_ws, size_t ws_size,
                              hipStream_t stream) {
  const float* x_H    = (const float*)d_in[0];
  const int*   ei_H   = (const int*)d_in[1];
  const float* x_G    = (const float*)d_in[2];
  const int*   ei_G   = (const int*)d_in[3];
  const int*   bat_H  = (const int*)d_in[4];
  const int*   bat_G  = (const int*)d_in[5];
  const float* sel_W1 = (const float*)d_in[6];
  const float* sel_b1 = (const float*)d_in[7];
  const float* sel_W2 = (const float*)d_in[8];
  const float* sel_b2 = (const float*)d_in[9];
  const float* sel_fcw = (const float*)d_in[10];
  const float* sel_fcb = (const float*)d_in[11];
  const float* emb_W1 = (const float*)d_in[12];
  const float* emb_b1 = (const float*)d_in[13];
  const float* emb_W2 = (const float*)d_in[14];
  const float* emb_b2 = (const float*)d_in[15];

  const int N = in_sizes[0] / FEAT;
  const int E = in_sizes[1] / 2;
  const int NG = 64;
  const int NB = (N + 127) >> BSHIFT;

  float* out = (float*)d_out;
  float* hF = out;
  float* hG = out + NG * FEAT;
  float* p  = out + 2 * NG * FEAT;

  char* ws = (char*)d_ws;
  size_t off = 0;
  auto alloc = [&](size_t bytes) -> void* {
    void* ptr = (void*)(ws + off);
    off += (bytes + 511) & ~(size_t)511;
    return ptr;
  };
  const size_t SZH = (size_t)N * FEAT * sizeof(h16);          // 25.6 MB
  const size_t SZP = (size_t)NB * CAP * sizeof(unsigned int); // 12.8 MB
  const size_t SZB = SZH > SZP ? SZH : SZP;
  h16* A       = (h16*)alloc(SZB);
  h16* B       = (h16*)alloc(SZB);
  h16* C       = (h16*)alloc(SZH);
  h16* x16H    = (h16*)alloc(SZH);
  float* dinvH = (float*)alloc((size_t)N * 4);
  float* dinvG = (float*)alloc((size_t)N * 4);
  int*  offsH  = (int*)alloc((size_t)(N + 1) * 4);
  int*  offsG  = (int*)alloc((size_t)(N + 1) * 4);
  int*  csrH   = (int*)alloc((size_t)E * 4);
  int*  csrG   = (int*)alloc((size_t)E * 4);
  int*  gcurH  = (int*)alloc((size_t)NB * 4);
  int*  gcurG  = (int*)alloc((size_t)NB * 4);
  int*  boffsH = (int*)alloc((size_t)(NB + 1) * 4);
  int*  boffsG = (int*)alloc((size_t)(NB + 1) * 4);
  float* part  = (float*)alloc((size_t)NG * PSL2 * FEAT * 4); // 1 MB
  h16* wtSel1  = (h16*)alloc((size_t)FEAT * FEAT * 2);
  h16* wtSel2  = (h16*)alloc((size_t)FEAT * FEAT * 2);
  h16* wtEmb1  = (h16*)alloc((size_t)FEAT * FEAT * 2);
  h16* wtEmb2  = (h16*)alloc((size_t)FEAT * FEAT * 2);
  (void)ws_size;

  unsigned int* pairH = (unsigned int*)A;
  unsigned int* pairG = (unsigned int*)B;

  const int gGemm = (N + 127) / 128;
  const int gAgg  = (N + 15) / 16;

  // ---- weight prep + x_H fp16 convert ----
  k_wprep<<<64, 256, 0, stream>>>(sel_W1, wtSel1);
  k_wprep<<<64, 256, 0, stream>>>(sel_W2, wtSel2);
  k_wprep<<<64, 256, 0, stream>>>(emb_W1, wtEmb1);
  k_wprep<<<64, 256, 0, stream>>>(emb_W2, wtEmb2);
  k_cvt<<<(N * FEAT / 8 + 255) / 256, 256, 0, stream>>>(x_H, x16H, N * FEAT / 8);

  // ---- build CSR for H and G ----
  hipMemsetAsync(gcurH, 0, (size_t)NB * 4, stream);
  hipMemsetAsync(gcurG, 0, (size_t)NB * 4, stream);
  k_part<<<256, 256, 0, stream>>>(ei_H, pairH, gcurH, E, NB);
  k_part<<<256, 256, 0, stream>>>(ei_G, pairG, gcurG, E, NB);
  k_bscan<<<1, 1024, 0, stream>>>(gcurH, boffsH, offsH, NB, N, E);
  k_bscan<<<1, 1024, 0, stream>>>(gcurG, boffsG, offsG, NB, N, E);
  k_bucket<<<NB, 256, 0, stream>>>(pairH, gcurH, boffsH, csrH, offsH, dinvH, N);
  k_bucket<<<NB, 256, 0, stream>>>(pairG, gcurG, boffsG, csrG, offsG, dinvG, N);

  // ---- selector: gemm1 -> agg -> gemm2 -> fused agg+pvec ----
  k_gemm_mfma<h16><<<gGemm, 256, 0, stream>>>(x16H, wtSel1, dinvH, nullptr, A, N);
  k_agg<<<gAgg, 256, 0, stream>>>(A, offsH, csrH, dinvH, sel_b1, B, N);
  k_gemm_mfma<h16><<<gGemm, 256, 0, stream>>>(B, wtSel2, dinvH, nullptr, C, N);
  k_agg_pvec<<<gAgg, 256, 0, stream>>>(C, offsH, csrH, dinvH, sel_b2, sel_fcw, sel_fcb, p, N);

  // ---- F branch: gemm1 -> agg -> gemm2 -> fused agg+pool ----
  k_gemm_mfma<h16><<<gGemm, 256, 0, stream>>>(x16H, wtEmb1, dinvH, p, A, N);
  k_agg<<<gAgg, 256, 0, stream>>>(A, offsH, csrH, dinvH, emb_b1, B, N);
  k_gemm_mfma<h16><<<gGemm, 256, 0, stream>>>(B, wtEmb2, dinvH, nullptr, C, N);
  k_agg_pool<<<NG * PSL2, 256, 0, stream>>>(C, offsH, csrH, dinvH, emb_b2, bat_H, part, N);
  k_pool_fin<<<NG, 128, 0, stream>>>(part, bat_H, hF, N);

  // ---- G branch ----
  k_gemm_mfma<float><<<gGemm, 256, 0, stream>>>(x_G, wtEmb1, dinvG, nullptr, A, N);
  k_agg<<<gAgg, 256, 0, stream>>>(A, offsG, csrG, dinvG, emb_b1, B, N);
  k_gemm_mfma<h16><<<gGemm, 256, 0, stream>>>(B, wtEmb2, dinvG, nullptr, C, N);
  k_agg_pool<<<NG * PSL2, 256, 0, stream>>>(C, offsG, csrG, dinvG, emb_b2, bat_G, part, N);
  k_pool_fin<<<NG, 128, 0, stream>>>(part, bat_G, hG, N);
}

// Round 14
// 615.211 us; speedup vs baseline: 1.2199x; 1.0483x over previous
//
#include <hip/hip_runtime.h>
#include <cstdint>
#include <cstddef>

#define FEAT 128
#define PSL2 32           // pool slices per graph
#define NGRAPH 64
#define BSHIFT 7          // 128 nodes per bucket
#define CAP 4096          // bucket capacity (mean 2048 for E=1.6M, N=100k)

typedef _Float16 h16;
typedef __attribute__((ext_vector_type(8))) _Float16 h16x8;
typedef __attribute__((ext_vector_type(4))) float f32x4;

// ---------- fp32 -> fp16 bulk convert (8 elems/thread) ----------
__global__ __launch_bounds__(256) void k_cvt(const float* __restrict__ X,
    h16* __restrict__ Y, int nv) {
  int i = blockIdx.x * 256 + threadIdx.x;
  if (i < nv) {
    const float* p = X + (size_t)i * 8;
    float4 a = *(const float4*)p, b = *(const float4*)(p + 4);
    h16x8 o;
    o[0] = (h16)a.x; o[1] = (h16)a.y; o[2] = (h16)a.z; o[3] = (h16)a.w;
    o[4] = (h16)b.x; o[5] = (h16)b.y; o[6] = (h16)b.z; o[7] = (h16)b.w;
    *(h16x8*)&Y[(size_t)i * 8] = o;
  }
}

// ---------- pass 1: block-level radix partition; packed (src<<7 | dstLocal) ----------
__global__ __launch_bounds__(256) void k_part(const int* __restrict__ ei,
    unsigned int* __restrict__ pair, int* __restrict__ gcur, int E, int nb) {
  __shared__ int cnt[1024];
  __shared__ int base[1024];
  int per = (E + gridDim.x - 1) / gridDim.x;
  int e0 = blockIdx.x * per;
  int e1 = min(e0 + per, E);
  for (int i = threadIdx.x; i < nb; i += 256) cnt[i] = 0;
  __syncthreads();
  for (int e = e0 + threadIdx.x; e < e1; e += 256)
    atomicAdd(&cnt[ei[E + e] >> BSHIFT], 1);
  __syncthreads();
  for (int i = threadIdx.x; i < nb; i += 256) {
    int c = cnt[i];
    base[i] = c ? atomicAdd(&gcur[i], c) : 0;
    cnt[i] = 0;   // reuse as intra-block cursor
  }
  __syncthreads();
  for (int e = e0 + threadIdx.x; e < e1; e += 256) {
    int src = ei[e];
    int dst = ei[E + e];
    int b = dst >> BSHIFT;
    int pos = base[b] + atomicAdd(&cnt[b], 1);
    if (pos < CAP) pair[(size_t)b * CAP + pos] = ((unsigned)src << BSHIFT) | (unsigned)(dst & 127);
  }
}

// ---------- small scan over bucket counts -> bucket offsets ----------
__global__ __launch_bounds__(1024) void k_bscan(const int* __restrict__ cnt,
    int* __restrict__ boffs, int* __restrict__ offs, int nb, int tailIdx, int tailVal) {
  __shared__ int wsum[16];
  __shared__ int carry;
  int tid = threadIdx.x;
  int lane = tid & 63;
  int wid = tid >> 6;
  if (tid == 0) carry = 0;
  for (int base = 0; base < nb; base += 1024) {
    __syncthreads();
    int c0 = carry;
    int i = base + tid;
    int v = (i < nb) ? cnt[i] : 0;
    int x = v;
#pragma unroll
    for (int off = 1; off < 64; off <<= 1) {
      int t = __shfl_up(x, off);
      if (lane >= off) x += t;
    }
    if (lane == 63) wsum[wid] = x;
    __syncthreads();
    if (wid == 0) {
      int t = (lane < 16) ? wsum[lane] : 0;
#pragma unroll
      for (int off = 1; off < 16; off <<= 1) {
        int u = __shfl_up(t, off);
        if (lane >= off) t += u;
      }
      if (lane < 16) wsum[lane] = t;
    }
    __syncthreads();
    int wex = (wid == 0) ? 0 : wsum[wid - 1];
    int o = c0 + wex + (x - v);
    if (i < nb) boffs[i] = o;
    int total = wsum[15];
    __syncthreads();
    if (tid == 0) carry = c0 + total;
  }
  __syncthreads();
  if (tid == 0) { boffs[nb] = carry; offs[tailIdx] = tailVal; }
}

// ---------- pass 2: per-bucket count/scan/scatter -> concatenated csr/offs/dinv ----------
__global__ __launch_bounds__(256) void k_bucket(const unsigned int* __restrict__ pair,
    const int* __restrict__ bcnt, const int* __restrict__ boffs,
    int* __restrict__ csr, int* __restrict__ offs, float* __restrict__ dinv,
    int N, int nodeOff, int edgeOff) {
  int b = blockIdx.x;
  int m = min(bcnt[b], CAP);
  __shared__ int cnt[128];
  __shared__ int noff[128];
  __shared__ int w0tot;
  if (threadIdx.x < 128) cnt[threadIdx.x] = 0;
  __syncthreads();
  const unsigned int* p = pair + (size_t)b * CAP;
  for (int i = threadIdx.x; i < m; i += 256)
    atomicAdd(&cnt[p[i] & 127u], 1);
  __syncthreads();
  int v = 0, x = 0;
  int lane = threadIdx.x & 63, w = threadIdx.x >> 6;
  if (threadIdx.x < 128) {
    v = cnt[threadIdx.x];
    x = v;
#pragma unroll
    for (int o = 1; o < 64; o <<= 1) {
      int t = __shfl_up(x, o);
      if (lane >= o) x += t;
    }
    if (threadIdx.x == 63) w0tot = x;
  }
  __syncthreads();
  int cbase = boffs[b] + edgeOff;
  if (threadIdx.x < 128) {
    int ex = x - v + ((w == 1) ? w0tot : 0);
    int g = (b << BSHIFT) + threadIdx.x;
    if (g < N) {
      offs[nodeOff + g] = cbase + ex;
      dinv[nodeOff + g] = 1.0f / sqrtf((float)v + 1.0f);
    }
    noff[threadIdx.x] = ex;
    cnt[threadIdx.x] = 0;
  }
  __syncthreads();
  for (int i = threadIdx.x; i < m; i += 256) {
    unsigned pk = p[i];
    int d = pk & 127u;
    int pos = cbase + noff[d] + atomicAdd(&cnt[d], 1);
    csr[pos] = (int)(pk >> BSHIFT) + nodeOff;
  }
}

// ---------- W prep: fp32 [k][col] -> fp16 transposed [col][k] ----------
__global__ __launch_bounds__(256) void k_wprep(const float* __restrict__ W,
    h16* __restrict__ WT) {
  int i = blockIdx.x * 256 + threadIdx.x;
  int k = i >> 7, c = i & 127;
  WT[c * FEAT + k] = (h16)W[(size_t)k * FEAT + c];
}

// ---------- gather core: 16 lanes/node, 16B (h16x8) per lane ----------
__device__ inline void acc8(f32x4& lo, f32x4& hi, h16x8 v) {
  lo[0] += (float)v[0]; lo[1] += (float)v[1]; lo[2] += (float)v[2]; lo[3] += (float)v[3];
  hi[0] += (float)v[4]; hi[1] += (float)v[5]; hi[2] += (float)v[6]; hi[3] += (float)v[7];
}

__device__ inline void gather_row8(const h16* __restrict__ XW,
    const int* __restrict__ offs, const int* __restrict__ csr,
    int node, int f0, f32x4& olo, f32x4& ohi) {
  f32x4 lo0 = {0,0,0,0}, hi0 = {0,0,0,0};
  f32x4 lo1 = {0,0,0,0}, hi1 = {0,0,0,0};
  f32x4 lo2 = {0,0,0,0}, hi2 = {0,0,0,0};
  f32x4 lo3 = {0,0,0,0}, hi3 = {0,0,0,0};
  h16x8 sv = *(const h16x8*)&XW[(size_t)node * FEAT + f0];   // self term
  acc8(lo0, hi0, sv);
  int s = offs[node], e = offs[node + 1];
  int i = s;
  for (; i + 8 <= e; i += 8) {
    int s0 = csr[i + 0], s1 = csr[i + 1], s2 = csr[i + 2], s3 = csr[i + 3];
    int s4 = csr[i + 4], s5 = csr[i + 5], s6 = csr[i + 6], s7 = csr[i + 7];
    h16x8 v0 = *(const h16x8*)&XW[(size_t)s0 * FEAT + f0];
    h16x8 v1 = *(const h16x8*)&XW[(size_t)s1 * FEAT + f0];
    h16x8 v2 = *(const h16x8*)&XW[(size_t)s2 * FEAT + f0];
    h16x8 v3 = *(const h16x8*)&XW[(size_t)s3 * FEAT + f0];
    h16x8 v4 = *(const h16x8*)&XW[(size_t)s4 * FEAT + f0];
    h16x8 v5 = *(const h16x8*)&XW[(size_t)s5 * FEAT + f0];
    h16x8 v6 = *(const h16x8*)&XW[(size_t)s6 * FEAT + f0];
    h16x8 v7 = *(const h16x8*)&XW[(size_t)s7 * FEAT + f0];
    acc8(lo0, hi0, v0); acc8(lo1, hi1, v1);
    acc8(lo2, hi2, v2); acc8(lo3, hi3, v3);
    acc8(lo0, hi0, v4); acc8(lo1, hi1, v5);
    acc8(lo2, hi2, v6); acc8(lo3, hi3, v7);
  }
  if (i + 4 <= e) {
    int s0 = csr[i + 0], s1 = csr[i + 1], s2 = csr[i + 2], s3 = csr[i + 3];
    h16x8 v0 = *(const h16x8*)&XW[(size_t)s0 * FEAT + f0];
    h16x8 v1 = *(const h16x8*)&XW[(size_t)s1 * FEAT + f0];
    h16x8 v2 = *(const h16x8*)&XW[(size_t)s2 * FEAT + f0];
    h16x8 v3 = *(const h16x8*)&XW[(size_t)s3 * FEAT + f0];
    acc8(lo0, hi0, v0); acc8(lo1, hi1, v1);
    acc8(lo2, hi2, v2); acc8(lo3, hi3, v3);
    i += 4;
  }
  for (; i < e; ++i) {
    int s0 = csr[i];
    h16x8 v0 = *(const h16x8*)&XW[(size_t)s0 * FEAT + f0];
    acc8(lo1, hi1, v0);
  }
  lo0[0]+=lo1[0]; lo0[1]+=lo1[1]; lo0[2]+=lo1[2]; lo0[3]+=lo1[3];
  hi0[0]+=hi1[0]; hi0[1]+=hi1[1]; hi0[2]+=hi1[2]; hi0[3]+=hi1[3];
  lo2[0]+=lo3[0]; lo2[1]+=lo3[1]; lo2[2]+=lo3[2]; lo2[3]+=lo3[3];
  hi2[0]+=hi3[0]; hi2[1]+=hi3[1]; hi2[2]+=hi3[2]; hi2[3]+=hi3[3];
  lo0[0]+=lo2[0]; lo0[1]+=lo2[1]; lo0[2]+=lo2[2]; lo0[3]+=lo2[3];
  hi0[0]+=hi2[0]; hi0[1]+=hi2[1]; hi0[2]+=hi2[2]; hi0[3]+=hi2[3];
  olo = lo0; ohi = hi0;
}

// -------- standalone aggregation: 16 nodes/block --------
__global__ __launch_bounds__(256) void k_agg(const h16* __restrict__ XW,
    const int* __restrict__ offs, const int* __restrict__ csr,
    const float* __restrict__ dinv, const float* __restrict__ bias,
    h16* __restrict__ out, int n) {
  int gid = threadIdx.x >> 4;
  int lane = threadIdx.x & 15;
  int node = blockIdx.x * 16 + gid;
  if (node >= n) return;
  int f0 = lane * 8;
  f32x4 lo, hi;
  gather_row8(XW, offs, csr, node, f0, lo, hi);
  float d = dinv[node];
  float4 b0 = *(const float4*)&bias[f0];
  float4 b1 = *(const float4*)&bias[f0 + 4];
  h16x8 o;
  o[0] = (h16)fmaxf(lo[0] * d + b0.x, 0.f);
  o[1] = (h16)fmaxf(lo[1] * d + b0.y, 0.f);
  o[2] = (h16)fmaxf(lo[2] * d + b0.z, 0.f);
  o[3] = (h16)fmaxf(lo[3] * d + b0.w, 0.f);
  o[4] = (h16)fmaxf(hi[0] * d + b1.x, 0.f);
  o[5] = (h16)fmaxf(hi[1] * d + b1.y, 0.f);
  o[6] = (h16)fmaxf(hi[2] * d + b1.z, 0.f);
  o[7] = (h16)fmaxf(hi[3] * d + b1.w, 0.f);
  *(h16x8*)&out[(size_t)node * FEAT + f0] = o;
}

// -------- fused aggregation + pvec (selector only) --------
__global__ __launch_bounds__(256) void k_agg_pvec(const h16* __restrict__ XW,
    const int* __restrict__ offs, const int* __restrict__ csr,
    const float* __restrict__ dinv, const float* __restrict__ bias,
    const float* __restrict__ fcw, const float* __restrict__ fcb,
    float* __restrict__ p, int n) {
  int gid = threadIdx.x >> 4;
  int lane = threadIdx.x & 15;
  int node = blockIdx.x * 16 + gid;
  if (node >= n) return;
  int f0 = lane * 8;
  f32x4 lo, hi;
  gather_row8(XW, offs, csr, node, f0, lo, hi);
  float d = dinv[node];
  float4 b0 = *(const float4*)&bias[f0];
  float4 b1 = *(const float4*)&bias[f0 + 4];
  float4 w0 = *(const float4*)&fcw[f0];
  float4 w1 = *(const float4*)&fcw[f0 + 4];
  float acc = fmaxf(lo[0] * d + b0.x, 0.f) * w0.x
            + fmaxf(lo[1] * d + b0.y, 0.f) * w0.y
            + fmaxf(lo[2] * d + b0.z, 0.f) * w0.z
            + fmaxf(lo[3] * d + b0.w, 0.f) * w0.w
            + fmaxf(hi[0] * d + b1.x, 0.f) * w1.x
            + fmaxf(hi[1] * d + b1.y, 0.f) * w1.y
            + fmaxf(hi[2] * d + b1.z, 0.f) * w1.z
            + fmaxf(hi[3] * d + b1.w, 0.f) * w1.w;
#pragma unroll
  for (int off = 8; off > 0; off >>= 1) acc += __shfl_xor(acc, off, 16);
  if (lane == 0) p[node] = 1.0f / (1.0f + expf(-(acc + fcb[0])));
}

// -------- batched final aggregation + mean-pool partial (128 graphs: 64 H + 64 G) --------
__global__ __launch_bounds__(256) void k_agg_pool(const h16* __restrict__ XW,
    const int* __restrict__ offs, const int* __restrict__ csr,
    const float* __restrict__ dinv, const float* __restrict__ bias,
    const int* __restrict__ batH, const int* __restrict__ batG,
    float* __restrict__ part, int n) {
  int gg = blockIdx.x / PSL2;
  int s = blockIdx.x % PSL2;
  const int* batch;
  int nodeBase, g;
  if (gg < NGRAPH) { batch = batH; nodeBase = 0; g = gg; }
  else             { batch = batG; nodeBase = n; g = gg - NGRAPH; }
  int lo_ = 0, hi_ = n;
  while (lo_ < hi_) { int m = (lo_ + hi_) >> 1; if (batch[m] < g) lo_ = m + 1; else hi_ = m; }
  int start = lo_;
  hi_ = n;
  while (lo_ < hi_) { int m = (lo_ + hi_) >> 1; if (batch[m] <= g) lo_ = m + 1; else hi_ = m; }
  int end = lo_;
  int len = end - start;
  int per = (len + PSL2 - 1) / PSL2;
  int r0 = start + s * per;
  int r1 = min(r0 + per, end);
  int gid = threadIdx.x >> 4;
  int lane = threadIdx.x & 15;
  int f0 = lane * 8;
  float4 b0 = *(const float4*)&bias[f0];
  float4 b1 = *(const float4*)&bias[f0 + 4];
  f32x4 plo = {0,0,0,0}, phi = {0,0,0,0};
  for (int node = r0 + gid; node < r1; node += 16) {
    int row = nodeBase + node;
    f32x4 lo, hi;
    gather_row8(XW, offs, csr, row, f0, lo, hi);
    float d = dinv[row];
    plo[0] += fmaxf(lo[0] * d + b0.x, 0.f);
    plo[1] += fmaxf(lo[1] * d + b0.y, 0.f);
    plo[2] += fmaxf(lo[2] * d + b0.z, 0.f);
    plo[3] += fmaxf(lo[3] * d + b0.w, 0.f);
    phi[0] += fmaxf(hi[0] * d + b1.x, 0.f);
    phi[1] += fmaxf(hi[1] * d + b1.y, 0.f);
    phi[2] += fmaxf(hi[2] * d + b1.z, 0.f);
    phi[3] += fmaxf(hi[3] * d + b1.w, 0.f);
  }
  __shared__ float lds[16 * FEAT];
  *(f32x4*)&lds[gid * FEAT + f0] = plo;
  *(f32x4*)&lds[gid * FEAT + f0 + 4] = phi;
  __syncthreads();
  if (threadIdx.x < FEAT) {
    int f = threadIdx.x;
    float t = 0.f;
#pragma unroll
    for (int q = 0; q < 16; ++q) t += lds[q * FEAT + f];
    part[(size_t)blockIdx.x * FEAT + f] = t;
  }
}

// ---------- pool finalize: 128 graphs -> hF / hG ----------
__global__ __launch_bounds__(128) void k_pool_fin(const float* __restrict__ part,
    const int* __restrict__ batH, const int* __restrict__ batG,
    float* __restrict__ hF, float* __restrict__ hG, int n) {
  int gg = blockIdx.x;
  const int* batch;
  float* outp;
  int g;
  if (gg < NGRAPH) { batch = batH; g = gg; outp = hF + (size_t)g * FEAT; }
  else             { batch = batG; g = gg - NGRAPH; outp = hG + (size_t)g * FEAT; }
  int lo = 0, hi = n;
  while (lo < hi) { int m = (lo + hi) >> 1; if (batch[m] < g) lo = m + 1; else hi = m; }
  int start = lo;
  hi = n;
  while (lo < hi) { int m = (lo + hi) >> 1; if (batch[m] <= g) lo = m + 1; else hi = m; }
  int len = lo - start;
  int f = threadIdx.x;
  float tot = 0.f;
#pragma unroll
  for (int s = 0; s < PSL2; ++s) tot += part[(size_t)(gg * PSL2 + s) * FEAT + f];
  outp[f] = tot / fmaxf((float)len, 1.0f);
}

// ---------------- MFMA GEMM (LDS-staged) ----------------
__device__ inline h16x8 load8(const h16* p) { return *(const h16x8*)p; }

__global__ __launch_bounds__(256) void k_gemm_mfma(const h16* __restrict__ X,
    const h16* __restrict__ WT, const float* __restrict__ s1,
    const float* __restrict__ s2, int s2n,
    h16* __restrict__ Y, int n) {
  __shared__ __align__(16) h16 lA[128 * FEAT];
  __shared__ __align__(16) h16 lB[128 * FEAT];
  int tid = threadIdx.x;
  int row0 = blockIdx.x * 128;
#pragma unroll
  for (int i = 0; i < 8; ++i) {
    int c = tid + i * 256;
    int r = c >> 4, kc = c & 15;
    int grow = row0 + r;
    h16x8 v;
#pragma unroll
    for (int j = 0; j < 8; ++j) v[j] = (h16)0.f;
    if (grow < n) v = load8(&X[(size_t)grow * FEAT + kc * 8]);
    int byte = r * 256 + ((kc * 16) ^ ((r & 7) << 4));
    *(h16x8*)((char*)lA + byte) = v;
  }
#pragma unroll
  for (int i = 0; i < 8; ++i) {
    int c = tid + i * 256;
    int col = c >> 4, kc = c & 15;
    h16x8 v = *(const h16x8*)&WT[col * FEAT + kc * 8];
    int byte = col * 256 + ((kc * 16) ^ ((col & 7) << 4));
    *(h16x8*)((char*)lB + byte) = v;
  }
  __syncthreads();
  int w = tid >> 6, l = tid & 63;
  int lr = l & 15, lq = l >> 4;
  h16x8 af[2][4];
#pragma unroll
  for (int m = 0; m < 2; ++m)
#pragma unroll
    for (int s = 0; s < 4; ++s) {
      int r = w * 32 + m * 16 + lr;
      int k2 = (s * 32 + lq * 8) * 2;
      int byte = r * 256 + (k2 ^ ((r & 7) << 4));
      af[m][s] = *(const h16x8*)((const char*)lA + byte);
    }
  f32x4 acc[2][8];
#pragma unroll
  for (int m = 0; m < 2; ++m)
#pragma unroll
    for (int nn = 0; nn < 8; ++nn) acc[m][nn] = (f32x4){0.f, 0.f, 0.f, 0.f};
#pragma unroll
  for (int nn = 0; nn < 8; ++nn) {
#pragma unroll
    for (int s = 0; s < 4; ++s) {
      int col = nn * 16 + lr;
      int k2 = (s * 32 + lq * 8) * 2;
      int byte = col * 256 + (k2 ^ ((col & 7) << 4));
      h16x8 bf = *(const h16x8*)((const char*)lB + byte);
      acc[0][nn] = __builtin_amdgcn_mfma_f32_16x16x32_f16(af[0][s], bf, acc[0][nn], 0, 0, 0);
      acc[1][nn] = __builtin_amdgcn_mfma_f32_16x16x32_f16(af[1][s], bf, acc[1][nn], 0, 0, 0);
    }
  }
#pragma unroll
  for (int m = 0; m < 2; ++m) {
#pragma unroll
    for (int r = 0; r < 4; ++r) {
      int grow = row0 + w * 32 + m * 16 + lq * 4 + r;
      if (grow < n) {
        float sc = 1.0f;
        if (s1) sc = s1[grow];
        if (s2 && grow < s2n) sc *= s2[grow];
#pragma unroll
        for (int nn = 0; nn < 8; ++nn)
          Y[(size_t)grow * FEAT + nn * 16 + lr] = (h16)(acc[m][nn][r] * sc);
      }
    }
  }
}

extern "C" void kernel_launch(void* const* d_in, const int* in_sizes, int n_in,
                              void* d_out, int out_size, void* d_ws, size_t ws_size,
                              hipStream_t stream) {
  const float* x_H    = (const float*)d_in[0];
  const int*   ei_H   = (const int*)d_in[1];
  const float* x_G    = (const float*)d_in[2];
  const int*   ei_G   = (const int*)d_in[3];
  const int*   bat_H  = (const int*)d_in[4];
  const int*   bat_G  = (const int*)d_in[5];
  const float* sel_W1 = (const float*)d_in[6];
  const float* sel_b1 = (const float*)d_in[7];
  const float* sel_W2 = (const float*)d_in[8];
  const float* sel_b2 = (const float*)d_in[9];
  const float* sel_fcw = (const float*)d_in[10];
  const float* sel_fcb = (const float*)d_in[11];
  const float* emb_W1 = (const float*)d_in[12];
  const float* emb_b1 = (const float*)d_in[13];
  const float* emb_W2 = (const float*)d_in[14];
  const float* emb_b2 = (const float*)d_in[15];

  const int N = in_sizes[0] / FEAT;
  const int E = in_sizes[1] / 2;
  const int N2 = 2 * N;
  const int NB = (N + 127) >> BSHIFT;

  float* out = (float*)d_out;
  float* hF = out;
  float* hG = out + NGRAPH * FEAT;
  float* p  = out + 2 * NGRAPH * FEAT;

  char* ws = (char*)d_ws;
  size_t off = 0;
  auto alloc = [&](size_t bytes) -> void* {
    void* ptr = (void*)(ws + off);
    off += (bytes + 511) & ~(size_t)511;
    return ptr;
  };
  const size_t SZ2 = (size_t)N2 * FEAT * sizeof(h16);   // 51.2 MB
  h16* XC      = (h16*)alloc(SZ2);    // x16 concat; later reused as FG agg1 output
  h16* A       = (h16*)alloc(SZ2);    // working buffer (also pair staging early)
  float* dinvC = (float*)alloc((size_t)N2 * 4);
  int*  offsC  = (int*)alloc((size_t)(N2 + 1) * 4);
  int*  csrC   = (int*)alloc((size_t)2 * E * 4);
  int*  gcurH  = (int*)alloc((size_t)NB * 4);
  int*  gcurG  = (int*)alloc((size_t)NB * 4);
  int*  boffsH = (int*)alloc((size_t)(NB + 1) * 4);
  int*  boffsG = (int*)alloc((size_t)(NB + 1) * 4);
  float* part  = (float*)alloc((size_t)2 * NGRAPH * PSL2 * FEAT * 4); // 2 MB
  h16* wtSel1  = (h16*)alloc((size_t)FEAT * FEAT * 2);
  h16* wtSel2  = (h16*)alloc((size_t)FEAT * FEAT * 2);
  h16* wtEmb1  = (h16*)alloc((size_t)FEAT * FEAT * 2);
  h16* wtEmb2  = (h16*)alloc((size_t)FEAT * FEAT * 2);
  (void)ws_size;

  // pair staging lives inside A (dead before first GEMM writes A)
  unsigned int* pairH = (unsigned int*)A;
  unsigned int* pairG = (unsigned int*)((char*)A + ((size_t)NB * CAP * 4 + 511 & ~(size_t)511));

  // selector ping-pong inside A: lo = rows [0,N), hi = rows [N,2N)
  h16* A_lo = A;
  h16* A_hi = A + (size_t)N * FEAT;

  const int gGemmN  = (N + 127) / 128;
  const int gGemm2N = (N2 + 127) / 128;
  const int gAggN   = (N + 15) / 16;
  const int gAgg2N  = (N2 + 15) / 16;

  // ---- weight prep + fp16 convert of both node-feature sets ----
  k_wprep<<<64, 256, 0, stream>>>(sel_W1, wtSel1);
  k_wprep<<<64, 256, 0, stream>>>(sel_W2, wtSel2);
  k_wprep<<<64, 256, 0, stream>>>(emb_W1, wtEmb1);
  k_wprep<<<64, 256, 0, stream>>>(emb_W2, wtEmb2);
  k_cvt<<<(N * FEAT / 8 + 255) / 256, 256, 0, stream>>>(x_H, XC, N * FEAT / 8);
  k_cvt<<<(N * FEAT / 8 + 255) / 256, 256, 0, stream>>>(x_G, XC + (size_t)N * FEAT, N * FEAT / 8);

  // ---- build concatenated CSR (H at [0,E), G at [E,2E) with +N node offset) ----
  hipMemsetAsync(gcurH, 0, (size_t)NB * 4, stream);
  hipMemsetAsync(gcurG, 0, (size_t)NB * 4, stream);
  k_part<<<256, 256, 0, stream>>>(ei_H, pairH, gcurH, E, NB);
  k_part<<<256, 256, 0, stream>>>(ei_G, pairG, gcurG, E, NB);
  k_bscan<<<1, 1024, 0, stream>>>(gcurH, boffsH, offsC, NB, N, E);
  k_bscan<<<1, 1024, 0, stream>>>(gcurG, boffsG, offsC, NB, N2, 2 * E);
  k_bucket<<<NB, 256, 0, stream>>>(pairH, gcurH, boffsH, csrC, offsC, dinvC, N, 0, 0);
  k_bucket<<<NB, 256, 0, stream>>>(pairG, gcurG, boffsG, csrC, offsC, dinvC, N, N, E);

  // ---- selector (H only): gemm1 -> agg -> gemm2 -> fused agg+pvec ----
  k_gemm_mfma<<<gGemmN, 256, 0, stream>>>(XC, wtSel1, dinvC, nullptr, 0, A_lo, N);
  k_agg<<<gAggN, 256, 0, stream>>>(A_lo, offsC, csrC, dinvC, sel_b1, A_hi, N);
  k_gemm_mfma<<<gGemmN, 256, 0, stream>>>(A_hi, wtSel2, dinvC, nullptr, 0, A_lo, N);
  k_agg_pvec<<<gAggN, 256, 0, stream>>>(A_lo, offsC, csrC, dinvC, sel_b2, sel_fcw, sel_fcb, p, N);

  // ---- F+G batched embed: gemm1 -> agg -> gemm2 -> agg+pool ----
  // rows [0,N) = x_H scaled by dinv*p ; rows [N,2N) = x_G scaled by dinv
  k_gemm_mfma<<<gGemm2N, 256, 0, stream>>>(XC, wtEmb1, dinvC, p, N, A, N2);
  k_agg<<<gAgg2N, 256, 0, stream>>>(A, offsC, csrC, dinvC, emb_b1, XC, N2);   // XC reused
  k_gemm_mfma<<<gGemm2N, 256, 0, stream>>>(XC, wtEmb2, dinvC, nullptr, 0, A, N2);
  k_agg_pool<<<2 * NGRAPH * PSL2, 256, 0, stream>>>(A, offsC, csrC, dinvC, emb_b2, bat_H, bat_G, part, N);
  k_pool_fin<<<2 * NGRAPH, 128, 0, stream>>>(part, bat_H, bat_G, hF, hG, N);
}